// Round 2
// baseline (3101.638 us; speedup 1.0000x reference)
//
#include <hip/hip_runtime.h>
#include <math.h>

#define NN 128
#define BLK 256

// Matrix stored row-major, 32 float4 units per row, XOR-swizzled: logical
// unit u of row r lives at physical unit (u ^ (r&7)). 64 lanes reading
// different rows at the same logical unit hit 32 distinct bank groups.
__device__ __forceinline__ int uidx(int r, int u) { return (r << 5) + (u ^ (r & 7)); }
__device__ __forceinline__ int eidx(int r, int c) {
  return (r << 7) + (((c >> 2) ^ (r & 7)) << 2) + (c & 3);
}

__device__ __forceinline__ double blockReduceSum(double v, double* red, int tid) {
  for (int off = 32; off > 0; off >>= 1) v += __shfl_down(v, off, 64);
  __syncthreads();                      // protect red[] from previous use
  if ((tid & 63) == 0) red[tid >> 6] = v;
  __syncthreads();
  return (red[0] + red[1]) + (red[2] + red[3]);
}

__device__ __forceinline__ float startvec(int i, int k) {
  unsigned h = (unsigned)(i * 1664525 + k * 1013904223 + 12345);
  h ^= h >> 13; h *= 2654435761u; h ^= h >> 16;
  return ((float)(h & 0xFFFFFFu) * (1.0f / 16777216.0f)) - 0.5f;
}

extern "C" __global__ void __launch_bounds__(BLK, 2)
holo_kernel(const float* __restrict__ A, const float* __restrict__ F,
            const float* __restrict__ swg, const float* __restrict__ curv,
            const float* __restrict__ W1, const float* __restrict__ Bb1,
            const float* __restrict__ W2, const float* __restrict__ Bb2,
            const float* __restrict__ OW1, const float* __restrict__ OB1,
            const float* __restrict__ OW2, const float* __restrict__ OB2,
            float* __restrict__ out, int B)
{
  __shared__ float4 mat4[NN * 32];                      // 64 KiB
  __shared__ double dd[NN], ee[NN], ee2[NN], tvec[NN], tauv[NN];
  __shared__ double red[4], sc[8], lam[20], blo[17], bhi[17];
  __shared__ int    bcnt[119];
  __shared__ __align__(16) float ufull[NN];
  __shared__ __align__(16) float qfull[NN];
  __shared__ __align__(16) float fscr[2 * NN];
  __shared__ __align__(16) float invdeg[NN];
  __shared__ float pbuf[NN];
  __shared__ float svec[NN], gvv[NN], hvv[NN], cw[NN];
  __shared__ double ssv[16], dred[16];
  __shared__ float msv[64], pool[16], zrow[16];

  float* matf = (float*)mat4;
  float* comb = fscr;            // reused after Householder phase
  float* hbuf = fscr + NN;

  const int  tid = threadIdx.x;
  const int  r   = tid & 127;    // row
  const int  h   = tid >> 7;     // column half (units 16h..16h+15)
  const long b   = blockIdx.x;
  const float* Ab = A + b * (long)(NN * NN);
  const float* Fb = F + b * (long)(NN * 64);

  // ---------------- load A (swizzled) ----------------
  {
    const float4* A4 = reinterpret_cast<const float4*>(Ab);
    for (int t = tid; t < NN * 32; t += BLK) {
      const int rr = t >> 5, u = t & 31;
      mat4[uidx(rr, u)] = A4[t];
    }
  }
  if (tid < NN) { ufull[tid] = 0.0f; qfull[tid] = 0.0f; }
  __syncthreads();

  // ---------------- degrees ----------------
  {
    double s = 0.0;
    for (int u = 16 * h; u < 16 * h + 16; ++u) {
      const float4 v = mat4[uidx(r, u)];
      s += (double)v.x + (double)v.y + (double)v.z + (double)v.w;
    }
    if (h) ee[r] = s; else dd[r] = s;
  }
  __syncthreads();
  if (tid < NN) {
    const double dg = dd[tid] + ee[tid] + 1e-8;
    invdeg[tid] = (float)(1.0 / dg);
    svec[tid]   = (float)(1.0 / sqrt(dg));
  }
  __syncthreads();
  // g = R^T 1 (A symmetric -> row dot invdeg)
  {
    const float4* iv4 = (const float4*)invdeg;
    double s = 0.0;
    for (int u = 16 * h; u < 16 * h + 16; ++u) {
      const float4 v = mat4[uidx(r, u)];
      const float4 w = iv4[u];
      s += (double)v.x * w.x + (double)v.y * w.y + (double)v.z * w.z + (double)v.w * w.w;
    }
    if (h) ee[r] = s; else dd[r] = s;
  }
  __syncthreads();
  if (tid < NN) gvv[tid] = (float)(dd[tid] + ee[tid]);
  __syncthreads();
  if (tid < NN) fscr[tid] = gvv[tid] * invdeg[tid];
  __syncthreads();
  // h = R^T g
  {
    const float4* w4 = (const float4*)fscr;
    double s = 0.0;
    for (int u = 16 * h; u < 16 * h + 16; ++u) {
      const float4 v = mat4[uidx(r, u)];
      const float4 w = w4[u];
      s += (double)v.x * w.x + (double)v.y * w.y + (double)v.z * w.z + (double)v.w * w.w;
    }
    if (h) ee[r] = s; else dd[r] = s;
  }
  __syncthreads();
  if (tid < NN) hvv[tid] = (float)(dd[tid] + ee[tid]);
  if (tid == 0) {
    const float a0 = swg[0], a1 = swg[1], a2 = swg[2];
    const float mx = fmaxf(a0, fmaxf(a1, a2));
    const float e0 = expf(a0 - mx), e1 = expf(a1 - mx), e2v = expf(a2 - mx);
    const float s = e0 + e1 + e2v;
    sc[0] = (double)(e0 / s); sc[1] = (double)(e1 / s); sc[2] = (double)(e2v / s);
  }
  __syncthreads();
  if (tid < NN)
    cw[tid] = ((float)sc[0] + (float)sc[1] * gvv[tid] + (float)sc[2] * hvv[tid]) * (1.0f / NN);
  __syncthreads();
  // ms[d] = sum_n cw[n] * F[n][d]  (4 quarter-row partials)
  {
    const int d = tid & 63, qt = tid >> 6;
    float acc = 0.0f;
    const float* fb = Fb + qt * 32 * 64;
    for (int n = 0; n < 32; ++n) acc = fmaf(cw[qt * 32 + n], fb[n * 64 + d], acc);
    fscr[tid] = acc;
  }
  __syncthreads();
  if (tid < 64) msv[tid] = (fscr[tid] + fscr[64 + tid]) + (fscr[128 + tid] + fscr[192 + tid]);
  __syncthreads();

  // ---------------- L = I - D^-1/2 A D^-1/2 ----------------
  for (int t = tid; t < NN * 32; t += BLK) {
    const int rr = t >> 5, u = t & 31;
    const int idx = uidx(rr, u);
    float4 v = mat4[idx];
    const float sr = svec[rr];
    const int c0 = u << 2;
    v.x = (rr == c0 + 0) ? 1.0f - v.x * sr * svec[c0 + 0] : -v.x * sr * svec[c0 + 0];
    v.y = (rr == c0 + 1) ? 1.0f - v.y * sr * svec[c0 + 1] : -v.y * sr * svec[c0 + 1];
    v.z = (rr == c0 + 2) ? 1.0f - v.z * sr * svec[c0 + 2] : -v.z * sr * svec[c0 + 2];
    v.w = (rr == c0 + 3) ? 1.0f - v.w * sr * svec[c0 + 3] : -v.w * sr * svec[c0 + 3];
    mat4[idx] = v;
  }
  __syncthreads();

  // ---------------- Householder tridiagonalization ----------------
  for (int k = 0; k < NN - 2; ++k) {
    float  xi = 0.0f;
    double part = 0.0;
    if (tid >= k + 1 && tid < NN) {
      xi = matf[eidx(tid, k)];
      if (tid > k + 1) part = (double)xi * (double)xi;
    }
    const double sig = blockReduceSum(part, red, tid);
    if (tid == 0) {
      const double alpha = (double)matf[eidx(k + 1, k)];
      dd[k] = (double)matf[eidx(k, k)];
      double beta, tau, scl;
      if (sig <= 0.0) { beta = alpha; tau = 0.0; scl = 0.0; }
      else {
        beta = -copysign(sqrt(alpha * alpha + sig), alpha);
        tau  = (beta - alpha) / beta;
        scl  = 1.0 / (alpha - beta);
      }
      ee[k] = beta; tauv[k] = tau; sc[0] = tau; sc[1] = scl;
    }
    __syncthreads();
    const float tauf = (float)sc[0];
    if (tid >= k + 1 && tid < NN) {
      const float uu = (tid == k + 1) ? 1.0f : xi * (float)sc[1];
      ufull[tid] = uu;
      matf[eidx(tid, k)] = uu;          // keep reflector for Q^T*1 sweep
    }
    if (tid == BLK - 1) { ufull[k] = 0.0f; qfull[k] = 0.0f; }  // clear stale entry
    __syncthreads();
    if (tauf != 0.0f) {                  // uniform branch
      // p_partial = (A u) over this thread's half-row
      {
        const int u0 = max(16 * h, (k + 1) >> 2), u1 = 16 * h + 16;
        float4 acc = make_float4(0.f, 0.f, 0.f, 0.f);
        if (r >= k + 1) {
          const float4* uf4 = (const float4*)ufull;
          for (int u = u0; u < u1; ++u) {
            const float4 a = mat4[uidx(r, u)];
            const float4 uv = uf4[u];
            acc.x = fmaf(a.x, uv.x, acc.x); acc.y = fmaf(a.y, uv.y, acc.y);
            acc.z = fmaf(a.z, uv.z, acc.z); acc.w = fmaf(a.w, uv.w, acc.w);
          }
        }
        fscr[tid] = (acc.x + acc.y) + (acc.z + acc.w);
      }
      __syncthreads();
      double up = 0.0;
      if (tid >= k + 1 && tid < NN) {
        const float p = tauf * (fscr[tid] + fscr[tid + NN]);   // p = tau*A*u
        pbuf[tid] = p;
        up = (double)ufull[tid] * (double)p;                   // own values, no barrier
      }
      const double upd = blockReduceSum(up, red, tid);
      if (tid == 0) sc[2] = 0.5 * (double)tauf * upd;
      __syncthreads();
      if (tid >= k + 1 && tid < NN)
        qfull[tid] = fmaf(-(float)sc[2], ufull[tid], pbuf[tid]);
      __syncthreads();
      // A -= u q^T + q u^T  (zero-padded q/u make boundary units safe)
      if (r >= k + 1) {
        const float ur = ufull[r], qr = qfull[r];
        const float4* uf4 = (const float4*)ufull;
        const float4* qf4 = (const float4*)qfull;
        const int u0 = max(16 * h, (k + 1) >> 2), u1 = 16 * h + 16;
        for (int u = u0; u < u1; ++u) {
          const int idx = uidx(r, u);
          float4 a = mat4[idx];
          const float4 uv = uf4[u], qv = qf4[u];
          a.x -= ur * qv.x + qr * uv.x;
          a.y -= ur * qv.y + qr * uv.y;
          a.z -= ur * qv.z + qr * uv.z;
          a.w -= ur * qv.w + qr * uv.w;
          mat4[idx] = a;
        }
      }
      __syncthreads();
    }
  }
  if (tid == 0) {
    dd[NN - 2] = (double)matf[eidx(NN - 2, NN - 2)];
    ee[NN - 2] = (double)matf[eidx(NN - 1, NN - 2)];
    dd[NN - 1] = (double)matf[eidx(NN - 1, NN - 1)];
    tauv[NN - 2] = 0.0;
  }
  __syncthreads();

  // ---------------- t = Q^T * ones (single wave) ----------------
  if (tid < NN) tvec[tid] = 1.0;
  __syncthreads();
  if (tid < 64) {
    for (int k = 0; k < NN - 2; ++k) {
      const int m = NN - 1 - k;
      const double tau = tauv[k];
      if (tau != 0.0) {
        double part = 0.0, u0 = 0.0, u1 = 0.0;
        const int i0 = tid, i1 = tid + 64;
        if (i0 < m) { u0 = (double)matf[eidx(k + 1 + i0, k)]; part += u0 * tvec[k + 1 + i0]; }
        if (i1 < m) { u1 = (double)matf[eidx(k + 1 + i1, k)]; part += u1 * tvec[k + 1 + i1]; }
        for (int off = 32; off > 0; off >>= 1) part += __shfl_down(part, off, 64);
        const double tw = tau * __shfl(part, 0, 64);
        if (i0 < m) tvec[k + 1 + i0] -= tw * u0;
        if (i1 < m) tvec[k + 1 + i1] -= tw * u1;
      }
    }
  }
  __syncthreads();

  // ---------------- bisection (multisection x7, 12 rounds) ----------------
  if (tid < NN - 1) ee2[tid] = ee[tid] * ee[tid];
  if (tid == 0) {
    double lo = 1e300, hi = -1e300;
    for (int i = 0; i < NN; ++i) {
      const double rr = ((i > 0) ? fabs(ee[i - 1]) : 0.0) + ((i < NN - 1) ? fabs(ee[i]) : 0.0);
      lo = fmin(lo, dd[i] - rr);
      hi = fmax(hi, dd[i] + rr);
    }
    sc[0] = lo - 1e-6; sc[1] = hi + 1e-6;
  }
  __syncthreads();
  if (tid < 17) { blo[tid] = sc[0]; bhi[tid] = sc[1]; }
  __syncthreads();
  for (int round = 0; round < 12; ++round) {
    if (tid < 119) {
      const int ke = tid / 7, j = tid % 7;
      const double lo = blo[ke], hi = bhi[ke];
      const double x = lo + (hi - lo) * ((double)(j + 1) * 0.125);
      int cnt = 0;
      double pm = 1.0, p = dd[0] - x;
      if (p < 0.0) cnt++;
      for (int i = 1; i < NN; ++i) {
        const double pn = (dd[i] - x) * p - ee2[i - 1] * pm;
        pm = p; p = pn;
        if ((p < 0.0) != (pm < 0.0)) cnt++;
        const double ap = fabs(p);
        if (ap > 1e100)                   { p *= 1e-100; pm *= 1e-100; }
        else if (ap < 1e-100 && ap > 0.0) { p *= 1e100;  pm *= 1e100; }
      }
      bcnt[tid] = cnt;
    }
    __syncthreads();
    if (tid < 17) {
      const double lo = blo[tid], hi = bhi[tid];
      const double w8 = (hi - lo) * 0.125;
      double nlo = lo, nhi = hi;
      for (int jj = 0; jj < 7; ++jj) {
        const double x = lo + w8 * (double)(jj + 1);
        if (bcnt[tid * 7 + jj] <= tid) nlo = x; else { nhi = x; break; }
      }
      blo[tid] = nlo; bhi[tid] = nhi;
    }
    __syncthreads();
  }
  if (tid < 17) lam[tid] = 0.5 * (blo[tid] + bhi[tid]);
  __syncthreads();

  // ---------------- inverse iteration on T (lanes 0..15) ----------------
  float* bu0 = matf;                 // reuse matrix LDS; stride-17 stripes
  float* bu1 = matf + NN * 17;
  float* bu2 = matf + 2 * NN * 17;
  float* byv = matf + 3 * NN * 17;

  if (tid < 16) {
    const double lk = lam[tid + 1];
    for (int it = 0; it < 2; ++it) {
      float beta = (float)(dd[0] - lk);
      float gam  = (float)ee[0];
      float rr   = (it == 0) ? startvec(0, tid) : byv[0 * 17 + tid];
      for (int i = 1; i < NN; ++i) {
        const float ai = (float)ee[i - 1];
        const float bi = (float)(dd[i] - lk);
        const float ci = (i < NN - 1) ? (float)ee[i] : 0.0f;
        const float ri = (it == 0) ? startvec(i, tid) : byv[i * 17 + tid];
        if (fabsf(beta) >= fabsf(ai)) {
          float piv = beta;
          if (piv == 0.0f) piv = 1e-25f;
          const float mm = ai / piv;
          bu0[(i - 1) * 17 + tid] = piv;
          bu1[(i - 1) * 17 + tid] = gam;
          bu2[(i - 1) * 17 + tid] = 0.0f;
          byv[(i - 1) * 17 + tid] = rr;
          beta = bi - mm * gam;  gam = ci;  rr = ri - mm * rr;
        } else {
          const float mm = beta / ai;
          bu0[(i - 1) * 17 + tid] = ai;
          bu1[(i - 1) * 17 + tid] = bi;
          bu2[(i - 1) * 17 + tid] = ci;
          byv[(i - 1) * 17 + tid] = ri;
          const float nb = gam - mm * bi;
          gam = -mm * ci;  beta = nb;  rr = rr - mm * ri;
        }
      }
      if (beta == 0.0f) beta = 1e-25f;
      bu0[(NN - 1) * 17 + tid] = beta;
      bu1[(NN - 1) * 17 + tid] = 0.0f;
      bu2[(NN - 1) * 17 + tid] = 0.0f;
      byv[(NN - 1) * 17 + tid] = rr;
      float y1 = 0.0f, y2 = 0.0f;
      for (int i = NN - 1; i >= 0; --i) {
        const float yy = (byv[i * 17 + tid] - bu1[i * 17 + tid] * y1 - bu2[i * 17 + tid] * y2)
                         / bu0[i * 17 + tid];
        byv[i * 17 + tid] = yy;
        y2 = y1; y1 = yy;
      }
      double nrm = 0.0;
      for (int i = 0; i < NN; ++i) { const double v = (double)byv[i * 17 + tid]; nrm += v * v; }
      const double inv = 1.0 / sqrt(nrm);
      for (int i = 0; i < NN; ++i) byv[i * 17 + tid] = (float)((double)byv[i * 17 + tid] * inv);
    }
  }
  __syncthreads();

  // ---------------- MGS ----------------
  for (int kk = 1; kk < 16; ++kk) {
    const int j = tid >> 3, s8 = tid & 7;
    double part = 0.0;
    if (j < kk)
      for (int i = s8 * 16; i < s8 * 16 + 16; ++i)
        part += (double)byv[i * 17 + j] * (double)byv[i * 17 + kk];
    for (int off = 4; off > 0; off >>= 1) part += __shfl_down(part, off, 8);
    __syncthreads();
    if (s8 == 0 && j < kk) dred[j] = part;
    __syncthreads();
    if (tid < NN) {
      double acc = (double)byv[tid * 17 + kk];
      for (int j2 = 0; j2 < kk; ++j2) acc -= dred[j2] * (double)byv[tid * 17 + j2];
      byv[tid * 17 + kk] = (float)acc;
    }
    __syncthreads();
    double p2 = 0.0;
    if (tid < NN) { const double v = (double)byv[tid * 17 + kk]; p2 = v * v; }
    const double n2 = blockReduceSum(p2, red, tid);
    if (tid < NN) byv[tid * 17 + kk] = (float)((double)byv[tid * 17 + kk] / sqrt(n2));
    __syncthreads();
  }

  // ---------------- s_k = t . y_k ; pooled ----------------
  if (tid < NN) {
    const int j = tid >> 3, s8 = tid & 7;
    double part = 0.0;
    for (int i = s8 * 16; i < s8 * 16 + 16; ++i)
      part += tvec[i] * (double)byv[i * 17 + j];
    for (int off = 4; off > 0; off >>= 1) part += __shfl_down(part, off, 8);
    if (s8 == 0) ssv[j] = part;
  }
  __syncthreads();
  if (tid == 0) {
    float lv[16], ev[16];
    float mx = -1e30f;
    for (int i = 0; i < 16; ++i) { lv[i] = (float)lam[i + 1]; mx = fmaxf(mx, -lv[i]); }
    float se = 0.0f;
    for (int i = 0; i < 16; ++i) { ev[i] = expf(-lv[i] - mx); se += ev[i]; }
    for (int i = 0; i < 16; ++i) pool[i] = (ev[i] / se) * (float)ssv[i];
  }
  __syncthreads();

  // ---------------- MLPs + outputs ----------------
  if (tid < NN) {
    float acc = Bb1[tid];
    for (int i = 0; i < 16; ++i) acc = fmaf(pool[i], W1[i * 128 + tid], acc);
    hbuf[tid] = fmaxf(acc, 0.0f);
  }
  __syncthreads();
  if (tid < 64) {
    float acc = Bb2[tid];
    for (int i = 0; i < 128; ++i) acc = fmaf(hbuf[i], W2[i * 64 + tid], acc);
    comb[tid] = acc;                       // spectral
  } else if (tid < NN) {
    comb[tid] = msv[tid - 64];             // ms
  }
  __syncthreads();
  if (tid < NN) {
    float acc = OB1[tid];
    for (int i = 0; i < 128; ++i) acc = fmaf(comb[i], OW1[i * 128 + tid], acc);
    hbuf[tid] = fmaxf(acc, 0.0f);
  }
  __syncthreads();
  if (tid < 16) {
    float acc = OB2[tid];
    for (int i = 0; i < 128; ++i) acc = fmaf(hbuf[i], OW2[i * 16 + tid], acc);
    zrow[tid] = acc;
  }
  __syncthreads();

  const long zeoff = (long)B * 16;
  const long spoff = (long)B * 32;
  const long svoff = (long)B * 32 + (long)B * 64;
  const long coff  = svoff + (long)B * 16;

  if (tid == 0) {
    const float c = 1.0f / (1.0f + expf(-curv[0]));
    float nrm = 0.0f;
    for (int i = 0; i < 16; ++i) nrm += zrow[i] * zrow[i];
    nrm = sqrtf(nrm);
    const float max_r = 0.95f / sqrtf(c);
    sc[3] = (double)fminf(1.0f, max_r / (nrm + 1e-12f));
    if (b == 0) out[coff] = c;
  }
  __syncthreads();
  if (tid < 16) {
    const float fac = (float)sc[3];
    out[b * 16 + tid]          = zrow[tid] * fac;     // z
    out[zeoff + b * 16 + tid]  = zrow[tid];           // z_euclidean
    out[svoff + b * 16 + tid]  = (float)lam[tid + 1]; // sel_vals
  }
  if (tid < 64) out[spoff + b * 64 + tid] = comb[tid]; // spectral
}

extern "C" void kernel_launch(void* const* d_in, const int* in_sizes, int n_in,
                              void* d_out, int out_size, void* d_ws, size_t ws_size,
                              hipStream_t stream) {
  const float* A    = (const float*)d_in[0];
  const float* F    = (const float*)d_in[1];
  const float* swg  = (const float*)d_in[2];
  const float* curv = (const float*)d_in[3];
  const float* W1   = (const float*)d_in[4];
  const float* Bb1  = (const float*)d_in[5];
  const float* W2   = (const float*)d_in[6];
  const float* Bb2  = (const float*)d_in[7];
  const float* OW1  = (const float*)d_in[8];
  const float* OB1  = (const float*)d_in[9];
  const float* OW2  = (const float*)d_in[10];
  const float* OB2  = (const float*)d_in[11];
  float* out = (float*)d_out;
  const int B = in_sizes[0] / (128 * 128);

  holo_kernel<<<dim3(B), dim3(BLK), 0, stream>>>(
      A, F, swg, curv, W1, Bb1, W2, Bb2, OW1, OB1, OW2, OB2, out, B);
}

// Round 3
// 1884.687 us; speedup vs baseline: 1.6457x; 1.6457x over previous
//
#include <hip/hip_runtime.h>
#include <math.h>

#define NN 128
#define BLK 256

__device__ __forceinline__ float hsum4(float4 v) { return (v.x + v.y) + (v.z + v.w); }

__device__ __forceinline__ double waveRedD(double v) {
#pragma unroll
  for (int off = 32; off > 0; off >>= 1) v += __shfl_down(v, off, 64);
  return v;
}

__device__ __forceinline__ float getc(float4 a, int c) {
  return (c == 0) ? a.x : (c == 1) ? a.y : (c == 2) ? a.z : a.w;
}

__device__ __forceinline__ double blockReduceSum(double v, double* red, int tid) {
  v = waveRedD(v);
  __syncthreads();
  if ((tid & 63) == 0) red[tid >> 6] = v;
  __syncthreads();
  return (red[0] + red[1]) + (red[2] + red[3]);
}

__device__ __forceinline__ float startvec(int i, int k) {
  unsigned h = (unsigned)(i * 1664525 + k * 1013904223 + 12345);
  h ^= h >> 13; h *= 2654435761u; h ^= h >> 16;
  return ((float)(h & 0xFFFFFFu) * (1.0f / 16777216.0f)) - 0.5f;
}

extern "C" __global__ void __launch_bounds__(BLK, 3)
holo_kernel(const float* __restrict__ A, const float* __restrict__ F,
            const float* __restrict__ swg, const float* __restrict__ curv,
            const float* __restrict__ W1, const float* __restrict__ Bb1,
            const float* __restrict__ W2, const float* __restrict__ Bb2,
            const float* __restrict__ OW1, const float* __restrict__ OB1,
            const float* __restrict__ OW2, const float* __restrict__ OB2,
            float* __restrict__ out, int B)
{
  __shared__ float  ws[4 * NN * 17];                    // 34816 B: invit workspace
  __shared__ double dscr[BLK];
  __shared__ __align__(16) float fscr[BLK];
  __shared__ double dd[NN], ee[NN], ee2[NN], tvec[NN];
  __shared__ double red[4], redup[2], redut[2], redsig[2], sc[8];
  __shared__ double lam[20], blo[17], bhi[17];
  __shared__ int    bcnt[119];
  __shared__ __align__(16) float ubuf[NN];
  __shared__ __align__(16) float pbuf[NN];
  __shared__ float  colk[NN];
  __shared__ __align__(16) float svec[NN];
  __shared__ __align__(16) float invdeg[NN];
  __shared__ float  gvv[NN], cw[NN];
  __shared__ double ssv[16], dred[16];
  __shared__ float  msv[64], pool[16], zrow[16];

  float* comb = fscr;            // reused after Householder
  float* hbuf = fscr + NN;

  const int  tid  = threadIdx.x;
  const int  r    = tid & 127;   // row owned
  const int  h    = tid >> 7;    // column half (cols 64h..64h+63)
  const int  lane = tid & 63;
  const int  wid  = tid >> 6;
  const long b    = blockIdx.x;
  const float* Ab = A + b * (long)(NN * NN);
  const float* Fb = F + b * (long)(NN * 64);

  // ---------------- load A: each thread owns half a row in registers ----------------
  float4 areg[16];
  {
    const float4* Arow = reinterpret_cast<const float4*>(Ab + (long)r * NN) + 16 * h;
#pragma unroll
    for (int uu = 0; uu < 16; ++uu) areg[uu] = Arow[uu];
  }
  if (tid == 0) {
    const float a0 = swg[0], a1 = swg[1], a2 = swg[2];
    const float mx = fmaxf(a0, fmaxf(a1, a2));
    const float e0 = expf(a0 - mx), e1 = expf(a1 - mx), e2v = expf(a2 - mx);
    const float s = e0 + e1 + e2v;
    sc[0] = (double)(e0 / s); sc[1] = (double)(e1 / s); sc[2] = (double)(e2v / s);
  }
  // ---------------- degrees ----------------
  {
    float4 s4 = make_float4(0.f, 0.f, 0.f, 0.f);
#pragma unroll
    for (int uu = 0; uu < 16; ++uu) {
      s4.x += areg[uu].x; s4.y += areg[uu].y; s4.z += areg[uu].z; s4.w += areg[uu].w;
    }
    dscr[tid] = (double)hsum4(s4);
  }
  __syncthreads();
  if (tid < NN) {
    const double dg = dscr[tid] + dscr[tid + NN] + 1e-8;
    invdeg[tid] = (float)(1.0 / dg);
    svec[tid]   = (float)(1.0 / sqrt(dg));
  }
  __syncthreads();
  // g = R^T 1 (A symmetric: row dot invdeg)
  {
    const float4* iv4 = (const float4*)invdeg;
    float4 acc = make_float4(0.f, 0.f, 0.f, 0.f);
#pragma unroll
    for (int uu = 0; uu < 16; ++uu) {
      const float4 a = areg[uu], w = iv4[16 * h + uu];
      acc.x = fmaf(a.x, w.x, acc.x); acc.y = fmaf(a.y, w.y, acc.y);
      acc.z = fmaf(a.z, w.z, acc.z); acc.w = fmaf(a.w, w.w, acc.w);
    }
    fscr[tid] = hsum4(acc);
  }
  __syncthreads();
  if (tid < NN) {
    const float gv = fscr[tid] + fscr[tid + NN];
    gvv[tid] = gv;
    ubuf[tid] = gv * invdeg[tid];
  }
  __syncthreads();
  // hv = R^T g
  {
    const float4* ub4 = (const float4*)ubuf;
    float4 acc = make_float4(0.f, 0.f, 0.f, 0.f);
#pragma unroll
    for (int uu = 0; uu < 16; ++uu) {
      const float4 a = areg[uu], w = ub4[16 * h + uu];
      acc.x = fmaf(a.x, w.x, acc.x); acc.y = fmaf(a.y, w.y, acc.y);
      acc.z = fmaf(a.z, w.z, acc.z); acc.w = fmaf(a.w, w.w, acc.w);
    }
    fscr[tid] = hsum4(acc);
  }
  __syncthreads();
  if (tid < NN) {
    const float hv = fscr[tid] + fscr[tid + NN];
    cw[tid] = ((float)sc[0] + (float)sc[1] * gvv[tid] + (float)sc[2] * hv) * (1.0f / NN);
  }
  __syncthreads();
  // ms[d] = sum_n cw[n] F[n][d]
  {
    const int d = tid & 63, qt = tid >> 6;
    float acc = 0.0f;
    const float* fb = Fb + qt * 32 * 64;
    for (int n = 0; n < 32; ++n) acc = fmaf(cw[qt * 32 + n], fb[n * 64 + d], acc);
    fscr[tid] = acc;
  }
  __syncthreads();
  if (tid < 64) msv[tid] = (fscr[tid] + fscr[64 + tid]) + (fscr[128 + tid] + fscr[192 + tid]);

  // ---------------- L = I - D^-1/2 A D^-1/2 (registers) ----------------
  {
    const float sr = svec[r];
    const float4* sv4p = (const float4*)svec;
#pragma unroll
    for (int uu = 0; uu < 16; ++uu) {
      const float4 sv = sv4p[16 * h + uu];
      float4 a = areg[uu];
      a.x = -a.x * sr * sv.x; a.y = -a.y * sr * sv.y;
      a.z = -a.z * sr * sv.z; a.w = -a.w * sr * sv.w;
      areg[uu] = a;
    }
    if ((r >> 6) == h) {                       // add identity on diagonal
      const int cl = r & 63, du = cl >> 2, dc = cl & 3;
#pragma unroll
      for (int uu = 0; uu < 16; ++uu) if (uu == du) {
        float4 a = areg[uu];
        a.x += (dc == 0) ? 1.f : 0.f; a.y += (dc == 1) ? 1.f : 0.f;
        a.z += (dc == 2) ? 1.f : 0.f; a.w += (dc == 3) ? 1.f : 0.f;
        areg[uu] = a;
      }
    }
  }
  // ---------------- prologue: column 0 extract + sigma + tvec init ----------------
  if (tid < NN) tvec[tid] = 1.0;
  if (h == 0) {
    const float v0 = areg[0].x;                // column 0 = unit 0, comp x
    colk[r] = v0;
    if (r == 0) dd[0] = (double)v0;
    double sigp = (r >= 2) ? (double)v0 * (double)v0 : 0.0;
    const double s = waveRedD(sigp);
    if (lane == 0) redsig[wid] = s;
  }
  __syncthreads();

  // ---------------- Householder: 4 barriers / iteration ----------------
  for (int k = 0; k < NN - 2; ++k) {
    // P2: redundant scalar head (all threads identical)
    const double sigma = redsig[0] + redsig[1];
    const double alpha = (double)colk[k + 1];
    double beta, tau, scl;
    if (sigma <= 0.0) { beta = alpha; tau = 0.0; scl = 0.0; }
    else {
      beta = -copysign(sqrt(alpha * alpha + sigma), alpha);
      tau  = (beta - alpha) / beta;
      scl  = 1.0 / (alpha - beta);
    }
    if (tid == 0) ee[k] = beta;
    const float sclf = (float)scl;
    const float tauf = (float)tau;
    if (h == 0) ubuf[r] = (r <= k) ? 0.f : (r == k + 1) ? 1.f : colk[r] * sclf;
    __syncthreads();                                   // A
    // P3: matvec partials (registers x broadcast u)
    {
      float4 acc = make_float4(0.f, 0.f, 0.f, 0.f);
      if (r >= k + 1 && 64 * h + 63 >= k + 1) {
        const float4* ub4 = (const float4*)ubuf;
#pragma unroll
        for (int uu = 0; uu < 16; ++uu) {
          const float4 a = areg[uu], u4 = ub4[16 * h + uu];
          acc.x = fmaf(a.x, u4.x, acc.x); acc.y = fmaf(a.y, u4.y, acc.y);
          acc.z = fmaf(a.z, u4.z, acc.z); acc.w = fmaf(a.w, u4.w, acc.w);
        }
      }
      fscr[tid] = hsum4(acc);
    }
    __syncthreads();                                   // B
    // P4: p = tau*A*u; reduce u.p and u.t
    {
      double upp = 0.0, utp = 0.0;
      if (h == 0) {
        const float p = tauf * (fscr[r] + fscr[r + NN]);
        pbuf[r] = p;
        const float uv = ubuf[r];
        upp = (double)uv * (double)p;
        utp = (double)uv * tvec[r];
      }
      const double s1 = waveRedD(upp);
      const double s2 = waveRedD(utp);
      if (h == 0 && lane == 0) { redup[wid] = s1; redut[wid] = s2; }
    }
    __syncthreads();                                   // C
    // P1: rank-2 update + tvec update + next-column extraction
    {
      const double upd = redup[0] + redup[1];
      const double utd = redut[0] + redut[1];
      const float  K   = (float)(0.5 * tau * upd);
      const double tut = tau * utd;
      if (r >= k + 1) {
        const float ur = ubuf[r];
        const float qr = fmaf(-K, ur, pbuf[r]);
        if (64 * h + 63 >= k + 1) {
          const float4* ub4 = (const float4*)ubuf;
          const float4* pb4 = (const float4*)pbuf;
#pragma unroll
          for (int uu = 0; uu < 16; ++uu) {
            const float4 u4 = ub4[16 * h + uu], p4 = pb4[16 * h + uu];
            float4 a = areg[uu];
            const float qx = fmaf(-K, u4.x, p4.x);
            const float qy = fmaf(-K, u4.y, p4.y);
            const float qz = fmaf(-K, u4.z, p4.z);
            const float qw = fmaf(-K, u4.w, p4.w);
            a.x -= ur * qx + qr * u4.x;
            a.y -= ur * qy + qr * u4.y;
            a.z -= ur * qz + qr * u4.z;
            a.w -= ur * qw + qr * u4.w;
            areg[uu] = a;
          }
        }
        if (h == 0) tvec[r] -= tut * (double)ubuf[r];
      }
      const int hstar = (k + 1) >> 6;                  // wave-uniform
      if (h == hstar) {
        double sigp = 0.0;
        if (r >= k + 1) {
          const int cl = (k + 1) - 64 * hstar, du = cl >> 2, dc = cl & 3;
          float val = 0.f;
#pragma unroll
          for (int uu = 0; uu < 16; ++uu) if (uu == du) val = getc(areg[uu], dc);
          if (r == k + 1) dd[k + 1] = (double)val;
          else {
            colk[r] = val;
            if (r >= k + 3) sigp = (double)val * (double)val;
          }
        }
        const double s = waveRedD(sigp);
        if (lane == 0) redsig[wid & 1] = s;
      }
    }
    __syncthreads();                                   // D
  }
  if (tid == 0)       ee[NN - 2] = (double)colk[NN - 1];
  if (tid == BLK - 1) dd[NN - 1] = (double)areg[15].w;   // r=127,h=1: col 127
  __syncthreads();

  // ---------------- bisection (multisection x7, 12 rounds) ----------------
  if (tid < NN - 1) ee2[tid] = ee[tid] * ee[tid];
  if (tid == 0) {
    double lo = 1e300, hi = -1e300;
    for (int i = 0; i < NN; ++i) {
      const double rr = ((i > 0) ? fabs(ee[i - 1]) : 0.0) + ((i < NN - 1) ? fabs(ee[i]) : 0.0);
      lo = fmin(lo, dd[i] - rr);
      hi = fmax(hi, dd[i] + rr);
    }
    sc[0] = lo - 1e-6; sc[1] = hi + 1e-6;
  }
  __syncthreads();
  if (tid < 17) { blo[tid] = sc[0]; bhi[tid] = sc[1]; }
  __syncthreads();
  for (int round = 0; round < 12; ++round) {
    if (tid < 119) {
      const int ke = tid / 7, j = tid % 7;
      const double lo = blo[ke], hi = bhi[ke];
      const double x = lo + (hi - lo) * ((double)(j + 1) * 0.125);
      int cnt = 0;
      double pm = 1.0, p = dd[0] - x;
      if (p < 0.0) cnt++;
      for (int i = 1; i < NN; ++i) {
        const double pn = (dd[i] - x) * p - ee2[i - 1] * pm;
        pm = p; p = pn;
        if ((p < 0.0) != (pm < 0.0)) cnt++;
        const double ap = fabs(p);
        if (ap > 1e100)                   { p *= 1e-100; pm *= 1e-100; }
        else if (ap < 1e-100 && ap > 0.0) { p *= 1e100;  pm *= 1e100; }
      }
      bcnt[tid] = cnt;
    }
    __syncthreads();
    if (tid < 17) {
      const double lo = blo[tid], hi = bhi[tid];
      const double w8 = (hi - lo) * 0.125;
      double nlo = lo, nhi = hi;
      for (int jj = 0; jj < 7; ++jj) {
        const double x = lo + w8 * (double)(jj + 1);
        if (bcnt[tid * 7 + jj] <= tid) nlo = x; else { nhi = x; break; }
      }
      blo[tid] = nlo; bhi[tid] = nhi;
    }
    __syncthreads();
  }
  if (tid < 17) lam[tid] = 0.5 * (blo[tid] + bhi[tid]);
  __syncthreads();

  // ---------------- inverse iteration on T (lanes 0..15) ----------------
  float* bu0 = ws;
  float* bu1 = ws + NN * 17;
  float* bu2 = ws + 2 * NN * 17;
  float* byv = ws + 3 * NN * 17;

  if (tid < 16) {
    const double lk = lam[tid + 1];
    for (int it = 0; it < 2; ++it) {
      float beta = (float)(dd[0] - lk);
      float gam  = (float)ee[0];
      float rr   = (it == 0) ? startvec(0, tid) : byv[0 * 17 + tid];
      for (int i = 1; i < NN; ++i) {
        const float ai = (float)ee[i - 1];
        const float bi = (float)(dd[i] - lk);
        const float ci = (i < NN - 1) ? (float)ee[i] : 0.0f;
        const float ri = (it == 0) ? startvec(i, tid) : byv[i * 17 + tid];
        if (fabsf(beta) >= fabsf(ai)) {
          float piv = beta;
          if (piv == 0.0f) piv = 1e-25f;
          const float mm = ai / piv;
          bu0[(i - 1) * 17 + tid] = piv;
          bu1[(i - 1) * 17 + tid] = gam;
          bu2[(i - 1) * 17 + tid] = 0.0f;
          byv[(i - 1) * 17 + tid] = rr;
          beta = bi - mm * gam;  gam = ci;  rr = ri - mm * rr;
        } else {
          const float mm = beta / ai;
          bu0[(i - 1) * 17 + tid] = ai;
          bu1[(i - 1) * 17 + tid] = bi;
          bu2[(i - 1) * 17 + tid] = ci;
          byv[(i - 1) * 17 + tid] = ri;
          const float nb = gam - mm * bi;
          gam = -mm * ci;  beta = nb;  rr = rr - mm * ri;
        }
      }
      if (beta == 0.0f) beta = 1e-25f;
      bu0[(NN - 1) * 17 + tid] = beta;
      bu1[(NN - 1) * 17 + tid] = 0.0f;
      bu2[(NN - 1) * 17 + tid] = 0.0f;
      byv[(NN - 1) * 17 + tid] = rr;
      float y1 = 0.0f, y2 = 0.0f;
      for (int i = NN - 1; i >= 0; --i) {
        const float yy = (byv[i * 17 + tid] - bu1[i * 17 + tid] * y1 - bu2[i * 17 + tid] * y2)
                         / bu0[i * 17 + tid];
        byv[i * 17 + tid] = yy;
        y2 = y1; y1 = yy;
      }
      double nrm = 0.0;
      for (int i = 0; i < NN; ++i) { const double v = (double)byv[i * 17 + tid]; nrm += v * v; }
      const double inv = 1.0 / sqrt(nrm);
      for (int i = 0; i < NN; ++i) byv[i * 17 + tid] = (float)((double)byv[i * 17 + tid] * inv);
    }
  }
  __syncthreads();

  // ---------------- MGS ----------------
  for (int kk = 1; kk < 16; ++kk) {
    const int j = tid >> 3, s8 = tid & 7;
    double part = 0.0;
    if (j < kk)
      for (int i = s8 * 16; i < s8 * 16 + 16; ++i)
        part += (double)byv[i * 17 + j] * (double)byv[i * 17 + kk];
    for (int off = 4; off > 0; off >>= 1) part += __shfl_down(part, off, 8);
    __syncthreads();
    if (s8 == 0 && j < kk) dred[j] = part;
    __syncthreads();
    if (tid < NN) {
      double acc = (double)byv[tid * 17 + kk];
      for (int j2 = 0; j2 < kk; ++j2) acc -= dred[j2] * (double)byv[tid * 17 + j2];
      byv[tid * 17 + kk] = (float)acc;
    }
    __syncthreads();
    double p2 = 0.0;
    if (tid < NN) { const double v = (double)byv[tid * 17 + kk]; p2 = v * v; }
    const double n2 = blockReduceSum(p2, red, tid);
    if (tid < NN) byv[tid * 17 + kk] = (float)((double)byv[tid * 17 + kk] / sqrt(n2));
    __syncthreads();
  }

  // ---------------- s_k = t . y_k ; pooled ----------------
  if (tid < NN) {
    const int j = tid >> 3, s8 = tid & 7;
    double part = 0.0;
    for (int i = s8 * 16; i < s8 * 16 + 16; ++i)
      part += tvec[i] * (double)byv[i * 17 + j];
    for (int off = 4; off > 0; off >>= 1) part += __shfl_down(part, off, 8);
    if (s8 == 0) ssv[j] = part;
  }
  __syncthreads();
  if (tid == 0) {
    float lv[16], ev[16];
    float mx = -1e30f;
    for (int i = 0; i < 16; ++i) { lv[i] = (float)lam[i + 1]; mx = fmaxf(mx, -lv[i]); }
    float se = 0.0f;
    for (int i = 0; i < 16; ++i) { ev[i] = expf(-lv[i] - mx); se += ev[i]; }
    for (int i = 0; i < 16; ++i) pool[i] = (ev[i] / se) * (float)ssv[i];
  }
  __syncthreads();

  // ---------------- MLPs + outputs ----------------
  if (tid < NN) {
    float acc = Bb1[tid];
    for (int i = 0; i < 16; ++i) acc = fmaf(pool[i], W1[i * 128 + tid], acc);
    hbuf[tid] = fmaxf(acc, 0.0f);
  }
  __syncthreads();
  if (tid < 64) {
    float acc = Bb2[tid];
    for (int i = 0; i < 128; ++i) acc = fmaf(hbuf[i], W2[i * 64 + tid], acc);
    comb[tid] = acc;                       // spectral
  } else if (tid < NN) {
    comb[tid] = msv[tid - 64];             // ms
  }
  __syncthreads();
  if (tid < NN) {
    float acc = OB1[tid];
    for (int i = 0; i < 128; ++i) acc = fmaf(comb[i], OW1[i * 128 + tid], acc);
    hbuf[tid] = fmaxf(acc, 0.0f);
  }
  __syncthreads();
  if (tid < 16) {
    float acc = OB2[tid];
    for (int i = 0; i < 128; ++i) acc = fmaf(hbuf[i], OW2[i * 16 + tid], acc);
    zrow[tid] = acc;
  }
  __syncthreads();

  const long zeoff = (long)B * 16;
  const long spoff = (long)B * 32;
  const long svoff = (long)B * 32 + (long)B * 64;
  const long coff  = svoff + (long)B * 16;

  if (tid == 0) {
    const float c = 1.0f / (1.0f + expf(-curv[0]));
    float nrm = 0.0f;
    for (int i = 0; i < 16; ++i) nrm += zrow[i] * zrow[i];
    nrm = sqrtf(nrm);
    const float max_r = 0.95f / sqrtf(c);
    sc[3] = (double)fminf(1.0f, max_r / (nrm + 1e-12f));
    if (b == 0) out[coff] = c;
  }
  __syncthreads();
  if (tid < 16) {
    const float fac = (float)sc[3];
    out[b * 16 + tid]          = zrow[tid] * fac;     // z
    out[zeoff + b * 16 + tid]  = zrow[tid];           // z_euclidean
    out[svoff + b * 16 + tid]  = (float)lam[tid + 1]; // sel_vals
  }
  if (tid < 64) out[spoff + b * 64 + tid] = comb[tid]; // spectral
}

extern "C" void kernel_launch(void* const* d_in, const int* in_sizes, int n_in,
                              void* d_out, int out_size, void* d_ws, size_t ws_size,
                              hipStream_t stream) {
  const float* A    = (const float*)d_in[0];
  const float* F    = (const float*)d_in[1];
  const float* swg  = (const float*)d_in[2];
  const float* curv = (const float*)d_in[3];
  const float* W1   = (const float*)d_in[4];
  const float* Bb1  = (const float*)d_in[5];
  const float* W2   = (const float*)d_in[6];
  const float* Bb2  = (const float*)d_in[7];
  const float* OW1  = (const float*)d_in[8];
  const float* OB1  = (const float*)d_in[9];
  const float* OW2  = (const float*)d_in[10];
  const float* OB2  = (const float*)d_in[11];
  float* out = (float*)d_out;
  const int B = in_sizes[0] / (128 * 128);

  holo_kernel<<<dim3(B), dim3(BLK), 0, stream>>>(
      A, F, swg, curv, W1, Bb1, W2, Bb2, OW1, OB1, OW2, OB2, out, B);
}

// Round 4
// 1784.826 us; speedup vs baseline: 1.7378x; 1.0560x over previous
//
#include <hip/hip_runtime.h>
#include <math.h>

#define NN 128
#define BLK 256

__device__ __forceinline__ float hsum4(float4 v) { return (v.x + v.y) + (v.z + v.w); }

__device__ __forceinline__ double waveRedD(double v) {
#pragma unroll
  for (int off = 32; off > 0; off >>= 1) v += __shfl_down(v, off, 64);
  return v;
}
__device__ __forceinline__ float waveRedF(float v) {
#pragma unroll
  for (int off = 32; off > 0; off >>= 1) v += __shfl_down(v, off, 64);
  return v;
}
__device__ __forceinline__ float getc(float4 a, int c) {
  return (c == 0) ? a.x : (c == 1) ? a.y : (c == 2) ? a.z : a.w;
}
__device__ __forceinline__ double blockReduceSum(double v, double* red, int tid) {
  v = waveRedD(v);
  __syncthreads();
  if ((tid & 63) == 0) red[tid >> 6] = v;
  __syncthreads();
  return (red[0] + red[1]) + (red[2] + red[3]);
}
__device__ __forceinline__ float startvec(int i, int k) {
  unsigned h = (unsigned)(i * 1664525 + k * 1013904223 + 12345);
  h ^= h >> 13; h *= 2654435761u; h ^= h >> 16;
  return ((float)(h & 0xFFFFFFu) * (1.0f / 16777216.0f)) - 0.5f;
}

extern "C" __global__ void __launch_bounds__(BLK, 5)
holo_kernel(const float* __restrict__ A, const float* __restrict__ F,
            const float* __restrict__ swg, const float* __restrict__ curv,
            const float* __restrict__ W1, const float* __restrict__ Bb1,
            const float* __restrict__ W2, const float* __restrict__ Bb2,
            const float* __restrict__ OW1, const float* __restrict__ OB1,
            const float* __restrict__ OW2, const float* __restrict__ OB2,
            float* __restrict__ out, int B)
{
  // Two big overlaid regions (8704 B each) + small fixed arrays. ~22.5 KB total.
  __shared__ __align__(16) float wsA[NN * 17];   // pre: dscr/svec/../ubuf/pbuf/colk; post: byv
  __shared__ __align__(16) float wsB[NN * 17];   // Householder: fscr; invit: sA; MLP: comb/hbuf
  __shared__ unsigned swb[16 * 5];               // pivot bits, 16 lanes x 4 words (stride 5)
  __shared__ double dd[NN], ee[NN], ee2[NN];
  __shared__ float  tvecf[NN];
  __shared__ double red[4], sc[8];
  __shared__ float  redupf[2], redutf[2], redsigf[2];
  __shared__ double lam[20], blo[17], bhi[17];
  __shared__ int    bcnt[119];
  __shared__ double ssv[16], dred[16];
  __shared__ float  msv[64], pool[16], zrow[16];

  double* dscr  = (double*)wsA;        // [256]  floats 0..511   (init only)
  float* svec   = wsA + 512;           // [128]
  float* invdeg = wsA + 640;           // [128]
  float* gvv    = wsA + 768;           // [128]
  float* cw     = wsA + 896;           // [128]
  float* ubuf   = wsA + 1024;          // [128]
  float* pbuf   = wsA + 1152;          // [128]
  float* colk   = wsA + 1280;          // [128]
  float* byv    = wsA;                 // [128*17] (after Householder)
  float* fscr   = wsB;                 // [256]    (during Householder)
  float* sA     = wsB;                 // [128*17] (invit LU store)
  float* comb   = wsB;                 // [128]    (MLP, after invit)
  float* hbuf   = wsB + 128;           // [128]

  const int  tid  = threadIdx.x;
  const int  r    = tid & 127;   // row owned
  const int  h    = tid >> 7;    // column half (cols 64h..64h+63)
  const int  lane = tid & 63;
  const int  wid  = tid >> 6;
  const long b    = blockIdx.x;
  const float* Ab = A + b * (long)(NN * NN);
  const float* Fb = F + b * (long)(NN * 64);

  // ---------------- load A: each thread owns half a row in registers ----------------
  float4 areg[16];
  {
    const float4* Arow = reinterpret_cast<const float4*>(Ab + (long)r * NN) + 16 * h;
#pragma unroll
    for (int uu = 0; uu < 16; ++uu) areg[uu] = Arow[uu];
  }
  if (tid == 0) {
    const float a0 = swg[0], a1 = swg[1], a2 = swg[2];
    const float mx = fmaxf(a0, fmaxf(a1, a2));
    const float e0 = expf(a0 - mx), e1 = expf(a1 - mx), e2v = expf(a2 - mx);
    const float s = e0 + e1 + e2v;
    sc[0] = (double)(e0 / s); sc[1] = (double)(e1 / s); sc[2] = (double)(e2v / s);
  }
  // ---------------- degrees ----------------
  {
    float4 s4 = make_float4(0.f, 0.f, 0.f, 0.f);
#pragma unroll
    for (int uu = 0; uu < 16; ++uu) {
      s4.x += areg[uu].x; s4.y += areg[uu].y; s4.z += areg[uu].z; s4.w += areg[uu].w;
    }
    dscr[tid] = (double)hsum4(s4);
  }
  __syncthreads();
  if (tid < NN) {
    const double dg = dscr[tid] + dscr[tid + NN] + 1e-8;
    invdeg[tid] = (float)(1.0 / dg);
    svec[tid]   = (float)(1.0 / sqrt(dg));
  }
  __syncthreads();
  // g = R^T 1 (A symmetric: row dot invdeg)
  {
    const float4* iv4 = (const float4*)invdeg;
    float4 acc = make_float4(0.f, 0.f, 0.f, 0.f);
#pragma unroll
    for (int uu = 0; uu < 16; ++uu) {
      const float4 a = areg[uu], w = iv4[16 * h + uu];
      acc.x = fmaf(a.x, w.x, acc.x); acc.y = fmaf(a.y, w.y, acc.y);
      acc.z = fmaf(a.z, w.z, acc.z); acc.w = fmaf(a.w, w.w, acc.w);
    }
    fscr[tid] = hsum4(acc);
  }
  __syncthreads();
  if (tid < NN) {
    const float gv = fscr[tid] + fscr[tid + NN];
    gvv[tid] = gv;
    ubuf[tid] = gv * invdeg[tid];
  }
  __syncthreads();
  // hv = R^T g
  {
    const float4* ub4 = (const float4*)ubuf;
    float4 acc = make_float4(0.f, 0.f, 0.f, 0.f);
#pragma unroll
    for (int uu = 0; uu < 16; ++uu) {
      const float4 a = areg[uu], w = ub4[16 * h + uu];
      acc.x = fmaf(a.x, w.x, acc.x); acc.y = fmaf(a.y, w.y, acc.y);
      acc.z = fmaf(a.z, w.z, acc.z); acc.w = fmaf(a.w, w.w, acc.w);
    }
    fscr[tid] = hsum4(acc);
  }
  __syncthreads();
  if (tid < NN) {
    const float hv = fscr[tid] + fscr[tid + NN];
    cw[tid] = ((float)sc[0] + (float)sc[1] * gvv[tid] + (float)sc[2] * hv) * (1.0f / NN);
  }
  __syncthreads();
  // ms[d] = sum_n cw[n] F[n][d]
  {
    const int d = tid & 63, qt = tid >> 6;
    float acc = 0.0f;
    const float* fb = Fb + qt * 32 * 64;
    for (int n = 0; n < 32; ++n) acc = fmaf(cw[qt * 32 + n], fb[n * 64 + d], acc);
    fscr[tid] = acc;
  }
  __syncthreads();
  if (tid < 64) msv[tid] = (fscr[tid] + fscr[64 + tid]) + (fscr[128 + tid] + fscr[192 + tid]);

  // ---------------- L = I - D^-1/2 A D^-1/2 (registers) ----------------
  {
    const float sr = svec[r];
    const float4* sv4p = (const float4*)svec;
#pragma unroll
    for (int uu = 0; uu < 16; ++uu) {
      const float4 sv = sv4p[16 * h + uu];
      float4 a = areg[uu];
      a.x = -a.x * sr * sv.x; a.y = -a.y * sr * sv.y;
      a.z = -a.z * sr * sv.z; a.w = -a.w * sr * sv.w;
      areg[uu] = a;
    }
    if ((r >> 6) == h) {                       // add identity on diagonal
      const int cl = r & 63, du = cl >> 2, dc = cl & 3;
#pragma unroll
      for (int uu = 0; uu < 16; ++uu) if (uu == du) {
        float4 a = areg[uu];
        a.x += (dc == 0) ? 1.f : 0.f; a.y += (dc == 1) ? 1.f : 0.f;
        a.z += (dc == 2) ? 1.f : 0.f; a.w += (dc == 3) ? 1.f : 0.f;
        areg[uu] = a;
      }
    }
  }
  // ---------------- prologue: column 0 extract + sigma + tvec init ----------------
  if (tid < NN) tvecf[tid] = 1.0f;
  if (h == 0) {
    const float v0 = areg[0].x;                // column 0
    colk[r] = v0;
    if (r == 0) dd[0] = (double)v0;
    const float s = waveRedF((r >= 2) ? v0 * v0 : 0.f);
    if (lane == 0) redsigf[wid] = s;
  }
  __syncthreads();

  // ---------------- Householder: 4 barriers / iteration ----------------
  for (int k = 0; k < NN - 2; ++k) {
    // P2: redundant scalar head (all threads identical)
    const float sigma  = redsigf[0] + redsigf[1];
    const float alphaf = colk[k + 1];
    double betad; float tauf, sclf;
    if (sigma <= 0.f) { betad = (double)alphaf; tauf = 0.f; sclf = 0.f; }
    else {
      betad = -copysign(sqrt((double)alphaf * (double)alphaf + (double)sigma), (double)alphaf);
      const float betaf = (float)betad;
      tauf = (betaf - alphaf) / betaf;
      sclf = 1.0f / (alphaf - betaf);
    }
    if (tid == 0) ee[k] = betad;
    if (h == 0) ubuf[r] = (r <= k) ? 0.f : (r == k + 1) ? 1.f : colk[r] * sclf;
    __syncthreads();                                   // A
    // P3: matvec partials (registers x broadcast u), per-unit static guards
    {
      float4 acc = make_float4(0.f, 0.f, 0.f, 0.f);
      if (r >= k + 1 && 64 * h + 63 >= k + 1 && tauf != 0.f) {
        const float4* ub4 = (const float4*)ubuf;
#pragma unroll
        for (int uu = 0; uu < 16; ++uu) {
          if (64 * h + 4 * uu + 3 >= k + 1) {          // unit has live columns
            const float4 a = areg[uu], u4 = ub4[16 * h + uu];
            acc.x = fmaf(a.x, u4.x, acc.x); acc.y = fmaf(a.y, u4.y, acc.y);
            acc.z = fmaf(a.z, u4.z, acc.z); acc.w = fmaf(a.w, u4.w, acc.w);
          }
        }
      }
      fscr[tid] = hsum4(acc);
    }
    __syncthreads();                                   // B
    // P4: p = tau*A*u; float reduces of u.p and u.t (waves 0,1)
    if (h == 0) {
      const float p = tauf * (fscr[r] + fscr[r + NN]);
      pbuf[r] = p;
      const float uv = ubuf[r];
      const float s1 = waveRedF(uv * p);
      const float s2 = waveRedF(uv * tvecf[r]);
      if (lane == 0) { redupf[wid] = s1; redutf[wid] = s2; }
    }
    __syncthreads();                                   // C
    // P1: rank-2 update + tvec update + next-column extraction
    {
      const float K   = 0.5f * tauf * (redupf[0] + redupf[1]);
      const float tut = tauf * (redutf[0] + redutf[1]);
      if (r >= k + 1) {
        const float ur = ubuf[r];
        const float qr = fmaf(-K, ur, pbuf[r]);
        if (64 * h + 63 >= k + 1) {
          const float4* ub4 = (const float4*)ubuf;
          const float4* pb4 = (const float4*)pbuf;
#pragma unroll
          for (int uu = 0; uu < 16; ++uu) {
            if (64 * h + 4 * uu + 3 >= k + 1) {
              const float4 u4 = ub4[16 * h + uu], p4 = pb4[16 * h + uu];
              float4 a = areg[uu];
              const float qx = fmaf(-K, u4.x, p4.x);
              const float qy = fmaf(-K, u4.y, p4.y);
              const float qz = fmaf(-K, u4.z, p4.z);
              const float qw = fmaf(-K, u4.w, p4.w);
              a.x -= ur * qx + qr * u4.x;
              a.y -= ur * qy + qr * u4.y;
              a.z -= ur * qz + qr * u4.z;
              a.w -= ur * qw + qr * u4.w;
              areg[uu] = a;
            }
          }
        }
        if (h == 0) tvecf[r] -= tut * ubuf[r];
      }
      const int hstar = (k + 1) >> 6;                  // wave-uniform
      if (h == hstar) {
        float sigp = 0.0f;
        if (r >= k + 1) {
          const int cl = (k + 1) - 64 * hstar, du = cl >> 2, dc = cl & 3;
          float val = 0.f;
#pragma unroll
          for (int uu = 0; uu < 16; ++uu) if (uu == du) val = getc(areg[uu], dc);
          if (r == k + 1) dd[k + 1] = (double)val;
          else {
            colk[r] = val;
            if (r >= k + 3) sigp = val * val;
          }
        }
        const float s = waveRedF(sigp);
        if (lane == 0) redsigf[wid & 1] = s;
      }
    }
    __syncthreads();                                   // D
  }
  if (tid == 0)       ee[NN - 2] = (double)colk[NN - 1];
  if (tid == BLK - 1) dd[NN - 1] = (double)areg[15].w;   // r=127,h=1: col 127
  __syncthreads();

  // ---------------- bisection (multisection x7, 11 rounds) ----------------
  if (tid < NN - 1) ee2[tid] = ee[tid] * ee[tid];
  if (tid == 0) {
    double lo = 1e300, hi = -1e300;
    for (int i = 0; i < NN; ++i) {
      const double rr = ((i > 0) ? fabs(ee[i - 1]) : 0.0) + ((i < NN - 1) ? fabs(ee[i]) : 0.0);
      lo = fmin(lo, dd[i] - rr);
      hi = fmax(hi, dd[i] + rr);
    }
    sc[4] = lo - 1e-6; sc[5] = hi + 1e-6;
  }
  __syncthreads();
  if (tid < 17) { blo[tid] = sc[4]; bhi[tid] = sc[5]; }
  __syncthreads();
  for (int round = 0; round < 11; ++round) {
    if (tid < 119) {
      const int ke = tid / 7, j = tid % 7;
      const double lo = blo[ke], hi = bhi[ke];
      const double x = lo + (hi - lo) * ((double)(j + 1) * 0.125);
      int cnt = 0;
      double pm = 1.0, p = dd[0] - x;
      if (p < 0.0) cnt++;
      for (int i = 1; i < NN; ++i) {
        const double pn = (dd[i] - x) * p - ee2[i - 1] * pm;
        pm = p; p = pn;
        if ((p < 0.0) != (pm < 0.0)) cnt++;
        const double ap = fabs(p);
        if (ap > 1e100)                   { p *= 1e-100; pm *= 1e-100; }
        else if (ap < 1e-100 && ap > 0.0) { p *= 1e100;  pm *= 1e100; }
      }
      bcnt[tid] = cnt;
    }
    __syncthreads();
    if (tid < 17) {
      const double lo = blo[tid], hi = bhi[tid];
      const double w8 = (hi - lo) * 0.125;
      double nlo = lo, nhi = hi;
      for (int jj = 0; jj < 7; ++jj) {
        const double x = lo + w8 * (double)(jj + 1);
        if (bcnt[tid * 7 + jj] <= tid) nlo = x; else { nhi = x; break; }
      }
      blo[tid] = nlo; bhi[tid] = nhi;
    }
    __syncthreads();
  }
  if (tid < 17) lam[tid] = 0.5 * (blo[tid] + bhi[tid]);
  __syncthreads();

  // ---------------- inverse iteration on T (lanes 0..15), compressed LU ----------------
  // Per row j: swap-bit swp[j]; sA[j] = swp[j] ? multiplier mm : pivot beta.
  // Reconstruction: u0 = swp? e[j] : sA[j]; u2 = swp&&j<126 ? e[j+1] : 0;
  //                 u1 = swp? (d[j+1]-lk) : (swp[j-1] ? -sA[j-1]*e[j] : e[j]) (e[127]:=0).
  if (tid < 16) {
    const double lk = lam[tid + 1];
    for (int it = 0; it < 2; ++it) {
      float beta = (float)(dd[0] - lk);
      float gam  = (float)ee[0];
      float rr   = (it == 0) ? startvec(0, tid) : byv[0 * 17 + tid];
      unsigned bw = 0;
      for (int i = 1; i < NN; ++i) {
        const int j = i - 1;
        const float ai = (float)ee[i - 1];
        const float bi = (float)(dd[i] - lk);
        const float ci = (i < NN - 1) ? (float)ee[i] : 0.0f;
        const float ri = (it == 0) ? startvec(i, tid) : byv[i * 17 + tid];
        if (fabsf(beta) >= fabsf(ai)) {
          float piv = (beta == 0.0f) ? 1e-25f : beta;
          const float mm = ai / piv;
          sA [j * 17 + tid] = piv;
          byv[j * 17 + tid] = rr;
          beta = bi - mm * gam;  gam = ci;  rr = ri - mm * rr;
        } else {
          const float mm = beta / ai;
          sA [j * 17 + tid] = mm;
          byv[j * 17 + tid] = ri;
          beta = gam - mm * bi;  gam = -mm * ci;  rr = rr - mm * ri;
          bw |= 1u << (j & 31);
        }
        if ((j & 31) == 31) { swb[tid * 5 + (j >> 5)] = bw; bw = 0; }
      }
      if (beta == 0.0f) beta = 1e-25f;
      sA [127 * 17 + tid] = beta;        // swp[127]=0
      byv[127 * 17 + tid] = rr;
      swb[tid * 5 + 3] = bw;             // bits 96..126 (+127=0)
      float y1 = 0.0f, y2 = 0.0f;
      for (int j = NN - 1; j >= 0; --j) {
        const bool sj = (swb[tid * 5 + (j >> 5)] >> (j & 31)) & 1;
        const bool sjm1 = (j > 0) ? ((swb[tid * 5 + ((j - 1) >> 5)] >> ((j - 1) & 31)) & 1) : false;
        float u0, u1, u2;
        if (sj) {
          u0 = (float)ee[j];
          u1 = (float)(dd[j + 1] - lk);
          u2 = (j < NN - 2) ? (float)ee[j + 1] : 0.0f;
        } else {
          u0 = sA[j * 17 + tid];
          const float ej = (j < NN - 1) ? (float)ee[j] : 0.0f;
          u1 = sjm1 ? (-sA[(j - 1) * 17 + tid] * ej) : ej;
          u2 = 0.0f;
        }
        const float yy = (byv[j * 17 + tid] - u1 * y1 - u2 * y2) / u0;
        byv[j * 17 + tid] = yy;
        y2 = y1; y1 = yy;
      }
      double nrm = 0.0;
      for (int i = 0; i < NN; ++i) { const double v = (double)byv[i * 17 + tid]; nrm += v * v; }
      const double inv = 1.0 / sqrt(nrm);
      for (int i = 0; i < NN; ++i) byv[i * 17 + tid] = (float)((double)byv[i * 17 + tid] * inv);
    }
  }
  __syncthreads();

  // ---------------- MGS ----------------
  for (int kk = 1; kk < 16; ++kk) {
    const int j = tid >> 3, s8 = tid & 7;
    double part = 0.0;
    if (j < kk)
      for (int i = s8 * 16; i < s8 * 16 + 16; ++i)
        part += (double)byv[i * 17 + j] * (double)byv[i * 17 + kk];
    for (int off = 4; off > 0; off >>= 1) part += __shfl_down(part, off, 8);
    __syncthreads();
    if (s8 == 0 && j < kk) dred[j] = part;
    __syncthreads();
    if (tid < NN) {
      double acc = (double)byv[tid * 17 + kk];
      for (int j2 = 0; j2 < kk; ++j2) acc -= dred[j2] * (double)byv[tid * 17 + j2];
      byv[tid * 17 + kk] = (float)acc;
    }
    __syncthreads();
    double p2 = 0.0;
    if (tid < NN) { const double v = (double)byv[tid * 17 + kk]; p2 = v * v; }
    const double n2 = blockReduceSum(p2, red, tid);
    if (tid < NN) byv[tid * 17 + kk] = (float)((double)byv[tid * 17 + kk] / sqrt(n2));
    __syncthreads();
  }

  // ---------------- s_k = t . y_k ; pooled ----------------
  if (tid < NN) {
    const int j = tid >> 3, s8 = tid & 7;
    double part = 0.0;
    for (int i = s8 * 16; i < s8 * 16 + 16; ++i)
      part += (double)tvecf[i] * (double)byv[i * 17 + j];
    for (int off = 4; off > 0; off >>= 1) part += __shfl_down(part, off, 8);
    if (s8 == 0) ssv[j] = part;
  }
  __syncthreads();
  if (tid == 0) {
    float lv[16], ev[16];
    float mx = -1e30f;
    for (int i = 0; i < 16; ++i) { lv[i] = (float)lam[i + 1]; mx = fmaxf(mx, -lv[i]); }
    float se = 0.0f;
    for (int i = 0; i < 16; ++i) { ev[i] = expf(-lv[i] - mx); se += ev[i]; }
    for (int i = 0; i < 16; ++i) pool[i] = (ev[i] / se) * (float)ssv[i];
  }
  __syncthreads();

  // ---------------- MLPs + outputs ----------------
  if (tid < NN) {
    float acc = Bb1[tid];
    for (int i = 0; i < 16; ++i) acc = fmaf(pool[i], W1[i * 128 + tid], acc);
    hbuf[tid] = fmaxf(acc, 0.0f);
  }
  __syncthreads();
  if (tid < 64) {
    float acc = Bb2[tid];
    for (int i = 0; i < 128; ++i) acc = fmaf(hbuf[i], W2[i * 64 + tid], acc);
    comb[tid] = acc;                       // spectral
  } else if (tid < NN) {
    comb[tid] = msv[tid - 64];             // ms
  }
  __syncthreads();
  if (tid < NN) {
    float acc = OB1[tid];
    for (int i = 0; i < 128; ++i) acc = fmaf(comb[i], OW1[i * 128 + tid], acc);
    hbuf[tid] = fmaxf(acc, 0.0f);
  }
  __syncthreads();
  if (tid < 16) {
    float acc = OB2[tid];
    for (int i = 0; i < 128; ++i) acc = fmaf(hbuf[i], OW2[i * 16 + tid], acc);
    zrow[tid] = acc;
  }
  __syncthreads();

  const long zeoff = (long)B * 16;
  const long spoff = (long)B * 32;
  const long svoff = (long)B * 32 + (long)B * 64;
  const long coff  = svoff + (long)B * 16;

  if (tid == 0) {
    const float c = 1.0f / (1.0f + expf(-curv[0]));
    float nrm = 0.0f;
    for (int i = 0; i < 16; ++i) nrm += zrow[i] * zrow[i];
    nrm = sqrtf(nrm);
    const float max_r = 0.95f / sqrtf(c);
    sc[3] = (double)fminf(1.0f, max_r / (nrm + 1e-12f));
    if (b == 0) out[coff] = c;
  }
  __syncthreads();
  if (tid < 16) {
    const float fac = (float)sc[3];
    out[b * 16 + tid]          = zrow[tid] * fac;     // z
    out[zeoff + b * 16 + tid]  = zrow[tid];           // z_euclidean
    out[svoff + b * 16 + tid]  = (float)lam[tid + 1]; // sel_vals
  }
  if (tid < 64) out[spoff + b * 64 + tid] = comb[tid]; // spectral
}

extern "C" void kernel_launch(void* const* d_in, const int* in_sizes, int n_in,
                              void* d_out, int out_size, void* d_ws, size_t ws_size,
                              hipStream_t stream) {
  const float* A    = (const float*)d_in[0];
  const float* F    = (const float*)d_in[1];
  const float* swg  = (const float*)d_in[2];
  const float* curv = (const float*)d_in[3];
  const float* W1   = (const float*)d_in[4];
  const float* Bb1  = (const float*)d_in[5];
  const float* W2   = (const float*)d_in[6];
  const float* Bb2  = (const float*)d_in[7];
  const float* OW1  = (const float*)d_in[8];
  const float* OB1  = (const float*)d_in[9];
  const float* OW2  = (const float*)d_in[10];
  const float* OB2  = (const float*)d_in[11];
  float* out = (float*)d_out;
  const int B = in_sizes[0] / (128 * 128);

  holo_kernel<<<dim3(B), dim3(BLK), 0, stream>>>(
      A, F, swg, curv, W1, Bb1, W2, Bb2, OW1, OB1, OW2, OB2, out, B);
}

// Round 5
// 1492.611 us; speedup vs baseline: 2.0780x; 1.1958x over previous
//
#include <hip/hip_runtime.h>
#include <math.h>

#define NN 128
#define BLK 256

__device__ __forceinline__ float hsum4(float4 v) { return (v.x + v.y) + (v.z + v.w); }

__device__ __forceinline__ double waveRedD(double v) {
#pragma unroll
  for (int off = 32; off > 0; off >>= 1) v += __shfl_down(v, off, 64);
  return v;
}
__device__ __forceinline__ float waveRedF(float v) {
#pragma unroll
  for (int off = 32; off > 0; off >>= 1) v += __shfl_down(v, off, 64);
  return v;
}
__device__ __forceinline__ float getc(float4 a, int c) {
  return (c == 0) ? a.x : (c == 1) ? a.y : (c == 2) ? a.z : a.w;
}
__device__ __forceinline__ double blockReduceSum(double v, double* red, int tid) {
  v = waveRedD(v);
  __syncthreads();
  if ((tid & 63) == 0) red[tid >> 6] = v;
  __syncthreads();
  return (red[0] + red[1]) + (red[2] + red[3]);
}
__device__ __forceinline__ float startvec(int i, int k) {
  unsigned h = (unsigned)(i * 1664525 + k * 1013904223 + 12345);
  h ^= h >> 13; h *= 2654435761u; h ^= h >> 16;
  return ((float)(h & 0xFFFFFFu) * (1.0f / 16777216.0f)) - 0.5f;
}

extern "C" __global__ void __launch_bounds__(BLK, 4)
holo_kernel(const float* __restrict__ A, const float* __restrict__ F,
            const float* __restrict__ swg, const float* __restrict__ curv,
            const float* __restrict__ W1, const float* __restrict__ Bb1,
            const float* __restrict__ W2, const float* __restrict__ Bb2,
            const float* __restrict__ OW1, const float* __restrict__ OB1,
            const float* __restrict__ OW2, const float* __restrict__ OB2,
            float* __restrict__ out, int B)
{
  // Two big overlaid regions (8704 B each) + small fixed arrays. ~22.5 KB total.
  __shared__ __align__(16) float wsA[NN * 17];   // pre: dscr/svec/../ubuf/pbuf/colk; post: byv
  __shared__ __align__(16) float wsB[NN * 17];   // Householder: fscr; invit: sA; MLP: comb/hbuf
  __shared__ unsigned swb[16 * 5];               // pivot bits, 16 lanes x 4 words (stride 5)
  __shared__ double dd[NN], ee[NN], ee2[NN];
  __shared__ float  tvecf[NN];
  __shared__ double red[4], sc[8];
  __shared__ float  redupf[2], redutf[2], redsigf[2];
  __shared__ double lam[20], blo[17], bhi[17];
  __shared__ int    bcnt[119];
  __shared__ double ssv[16], dred[16];
  __shared__ float  msv[64], pool[16], zrow[16];

  double* dscr  = (double*)wsA;        // [256]  floats 0..511   (init only)
  float* svec   = wsA + 512;           // [128]
  float* invdeg = wsA + 640;           // [128]
  float* gvv    = wsA + 768;           // [128]
  float* cw     = wsA + 896;           // [128]
  float* ubuf   = wsA + 1024;          // [128]
  float* pbuf   = wsA + 1152;          // [128]
  float* colk   = wsA + 1280;          // [128]
  float* byv    = wsA;                 // [128*17] (after Householder)
  float* fscr   = wsB;                 // [256]    (during Householder)
  float* sA     = wsB;                 // [128*17] (invit LU store)
  float* comb   = wsB;                 // [128]    (MLP, after invit)
  float* hbuf   = wsB + 128;           // [128]

  const int  tid  = threadIdx.x;
  const int  r    = tid & 127;   // row owned
  const int  h    = tid >> 7;    // column half (cols 64h..64h+63)
  const int  lane = tid & 63;
  const int  wid  = tid >> 6;
  const long b    = blockIdx.x;
  const float* Ab = A + b * (long)(NN * NN);
  const float* Fb = F + b * (long)(NN * 64);

  // ---------------- load A: each thread owns half a row in registers ----------------
  float4 areg[16];
  {
    const float4* Arow = reinterpret_cast<const float4*>(Ab + (long)r * NN) + 16 * h;
#pragma unroll
    for (int uu = 0; uu < 16; ++uu) areg[uu] = Arow[uu];
  }
  if (tid == 0) {
    const float a0 = swg[0], a1 = swg[1], a2 = swg[2];
    const float mx = fmaxf(a0, fmaxf(a1, a2));
    const float e0 = expf(a0 - mx), e1 = expf(a1 - mx), e2v = expf(a2 - mx);
    const float s = e0 + e1 + e2v;
    sc[0] = (double)(e0 / s); sc[1] = (double)(e1 / s); sc[2] = (double)(e2v / s);
  }
  // ---------------- degrees ----------------
  {
    float4 s4 = make_float4(0.f, 0.f, 0.f, 0.f);
#pragma unroll
    for (int uu = 0; uu < 16; ++uu) {
      s4.x += areg[uu].x; s4.y += areg[uu].y; s4.z += areg[uu].z; s4.w += areg[uu].w;
    }
    dscr[tid] = (double)hsum4(s4);
  }
  __syncthreads();
  if (tid < NN) {
    const double dg = dscr[tid] + dscr[tid + NN] + 1e-8;
    invdeg[tid] = (float)(1.0 / dg);
    svec[tid]   = (float)(1.0 / sqrt(dg));
  }
  __syncthreads();
  // g = R^T 1 (A symmetric: row dot invdeg)
  {
    const float4* iv4 = (const float4*)invdeg;
    float4 acc = make_float4(0.f, 0.f, 0.f, 0.f);
#pragma unroll
    for (int uu = 0; uu < 16; ++uu) {
      const float4 a = areg[uu], w = iv4[16 * h + uu];
      acc.x = fmaf(a.x, w.x, acc.x); acc.y = fmaf(a.y, w.y, acc.y);
      acc.z = fmaf(a.z, w.z, acc.z); acc.w = fmaf(a.w, w.w, acc.w);
    }
    fscr[tid] = hsum4(acc);
  }
  __syncthreads();
  if (tid < NN) {
    const float gv = fscr[tid] + fscr[tid + NN];
    gvv[tid] = gv;
    ubuf[tid] = gv * invdeg[tid];
  }
  __syncthreads();
  // hv = R^T g
  {
    const float4* ub4 = (const float4*)ubuf;
    float4 acc = make_float4(0.f, 0.f, 0.f, 0.f);
#pragma unroll
    for (int uu = 0; uu < 16; ++uu) {
      const float4 a = areg[uu], w = ub4[16 * h + uu];
      acc.x = fmaf(a.x, w.x, acc.x); acc.y = fmaf(a.y, w.y, acc.y);
      acc.z = fmaf(a.z, w.z, acc.z); acc.w = fmaf(a.w, w.w, acc.w);
    }
    fscr[tid] = hsum4(acc);
  }
  __syncthreads();
  if (tid < NN) {
    const float hv = fscr[tid] + fscr[tid + NN];
    cw[tid] = ((float)sc[0] + (float)sc[1] * gvv[tid] + (float)sc[2] * hv) * (1.0f / NN);
  }
  __syncthreads();
  // ms[d] = sum_n cw[n] F[n][d]
  {
    const int d = tid & 63, qt = tid >> 6;
    float acc = 0.0f;
    const float* fb = Fb + qt * 32 * 64;
    for (int n = 0; n < 32; ++n) acc = fmaf(cw[qt * 32 + n], fb[n * 64 + d], acc);
    fscr[tid] = acc;
  }
  __syncthreads();
  if (tid < 64) msv[tid] = (fscr[tid] + fscr[64 + tid]) + (fscr[128 + tid] + fscr[192 + tid]);

  // ---------------- L = I - D^-1/2 A D^-1/2 (registers) ----------------
  {
    const float sr = svec[r];
    const float4* sv4p = (const float4*)svec;
#pragma unroll
    for (int uu = 0; uu < 16; ++uu) {
      const float4 sv = sv4p[16 * h + uu];
      float4 a = areg[uu];
      a.x = -a.x * sr * sv.x; a.y = -a.y * sr * sv.y;
      a.z = -a.z * sr * sv.z; a.w = -a.w * sr * sv.w;
      areg[uu] = a;
    }
    if ((r >> 6) == h) {                       // add identity on diagonal
      const int cl = r & 63, du = cl >> 2, dc = cl & 3;
#pragma unroll
      for (int uu = 0; uu < 16; ++uu) if (uu == du) {
        float4 a = areg[uu];
        a.x += (dc == 0) ? 1.f : 0.f; a.y += (dc == 1) ? 1.f : 0.f;
        a.z += (dc == 2) ? 1.f : 0.f; a.w += (dc == 3) ? 1.f : 0.f;
        areg[uu] = a;
      }
    }
  }
  // ---------------- prologue: column 0 extract + sigma + tvec init ----------------
  if (tid < NN) tvecf[tid] = 1.0f;
  if (h == 0) {
    const float v0 = areg[0].x;                // column 0
    colk[r] = v0;
    if (r == 0) dd[0] = (double)v0;
    const float s = waveRedF((r >= 2) ? v0 * v0 : 0.f);
    if (lane == 0) redsigf[wid] = s;
  }
  __syncthreads();

  // ---------------- Householder: 4 barriers / iteration ----------------
  for (int k = 0; k < NN - 2; ++k) {
    // P2: redundant scalar head (all threads identical)
    const float sigma  = redsigf[0] + redsigf[1];
    const float alphaf = colk[k + 1];
    double betad; float tauf, sclf;
    if (sigma <= 0.f) { betad = (double)alphaf; tauf = 0.f; sclf = 0.f; }
    else {
      betad = -copysign(sqrt((double)alphaf * (double)alphaf + (double)sigma), (double)alphaf);
      const float betaf = (float)betad;
      tauf = (betaf - alphaf) / betaf;
      sclf = 1.0f / (alphaf - betaf);
    }
    if (tid == 0) ee[k] = betad;
    if (h == 0) ubuf[r] = (r <= k) ? 0.f : (r == k + 1) ? 1.f : colk[r] * sclf;
    __syncthreads();                                   // A
    // P3: matvec partials (registers x broadcast u), per-unit static guards
    {
      float4 acc = make_float4(0.f, 0.f, 0.f, 0.f);
      if (r >= k + 1 && 64 * h + 63 >= k + 1 && tauf != 0.f) {
        const float4* ub4 = (const float4*)ubuf;
#pragma unroll
        for (int uu = 0; uu < 16; ++uu) {
          if (64 * h + 4 * uu + 3 >= k + 1) {          // unit has live columns
            const float4 a = areg[uu], u4 = ub4[16 * h + uu];
            acc.x = fmaf(a.x, u4.x, acc.x); acc.y = fmaf(a.y, u4.y, acc.y);
            acc.z = fmaf(a.z, u4.z, acc.z); acc.w = fmaf(a.w, u4.w, acc.w);
          }
        }
      }
      fscr[tid] = hsum4(acc);
    }
    __syncthreads();                                   // B
    // P4: p = tau*A*u; float reduces of u.p and u.t (waves 0,1)
    if (h == 0) {
      const float p = tauf * (fscr[r] + fscr[r + NN]);
      pbuf[r] = p;
      const float uv = ubuf[r];
      const float s1 = waveRedF(uv * p);
      const float s2 = waveRedF(uv * tvecf[r]);
      if (lane == 0) { redupf[wid] = s1; redutf[wid] = s2; }
    }
    __syncthreads();                                   // C
    // P1: rank-2 update + tvec update + next-column extraction
    {
      const float K   = 0.5f * tauf * (redupf[0] + redupf[1]);
      const float tut = tauf * (redutf[0] + redutf[1]);
      if (r >= k + 1) {
        const float ur = ubuf[r];
        const float qr = fmaf(-K, ur, pbuf[r]);
        if (64 * h + 63 >= k + 1) {
          const float4* ub4 = (const float4*)ubuf;
          const float4* pb4 = (const float4*)pbuf;
#pragma unroll
          for (int uu = 0; uu < 16; ++uu) {
            if (64 * h + 4 * uu + 3 >= k + 1) {
              const float4 u4 = ub4[16 * h + uu], p4 = pb4[16 * h + uu];
              float4 a = areg[uu];
              const float qx = fmaf(-K, u4.x, p4.x);
              const float qy = fmaf(-K, u4.y, p4.y);
              const float qz = fmaf(-K, u4.z, p4.z);
              const float qw = fmaf(-K, u4.w, p4.w);
              a.x -= ur * qx + qr * u4.x;
              a.y -= ur * qy + qr * u4.y;
              a.z -= ur * qz + qr * u4.z;
              a.w -= ur * qw + qr * u4.w;
              areg[uu] = a;
            }
          }
        }
        if (h == 0) tvecf[r] -= tut * ubuf[r];
      }
      const int hstar = (k + 1) >> 6;                  // wave-uniform
      if (h == hstar) {
        float sigp = 0.0f;
        if (r >= k + 1) {
          const int cl = (k + 1) - 64 * hstar, du = cl >> 2, dc = cl & 3;
          float val = 0.f;
#pragma unroll
          for (int uu = 0; uu < 16; ++uu) if (uu == du) val = getc(areg[uu], dc);
          if (r == k + 1) dd[k + 1] = (double)val;
          else {
            colk[r] = val;
            if (r >= k + 3) sigp = val * val;
          }
        }
        const float s = waveRedF(sigp);
        if (lane == 0) redsigf[wid & 1] = s;
      }
    }
    __syncthreads();                                   // D
  }
  if (tid == 0)       ee[NN - 2] = (double)colk[NN - 1];
  if (tid == BLK - 1) dd[NN - 1] = (double)areg[15].w;   // r=127,h=1: col 127
  __syncthreads();

  // ---------------- bisection (multisection x7, 11 rounds) ----------------
  if (tid < NN - 1) ee2[tid] = ee[tid] * ee[tid];
  if (tid == 0) {
    double lo = 1e300, hi = -1e300;
    for (int i = 0; i < NN; ++i) {
      const double rr = ((i > 0) ? fabs(ee[i - 1]) : 0.0) + ((i < NN - 1) ? fabs(ee[i]) : 0.0);
      lo = fmin(lo, dd[i] - rr);
      hi = fmax(hi, dd[i] + rr);
    }
    sc[4] = lo - 1e-6; sc[5] = hi + 1e-6;
  }
  __syncthreads();
  if (tid < 17) { blo[tid] = sc[4]; bhi[tid] = sc[5]; }
  __syncthreads();
  for (int round = 0; round < 11; ++round) {
    if (tid < 119) {
      const int ke = tid / 7, j = tid % 7;
      const double lo = blo[ke], hi = bhi[ke];
      const double x = lo + (hi - lo) * ((double)(j + 1) * 0.125);
      int cnt = 0;
      double pm = 1.0, p = dd[0] - x;
      if (p < 0.0) cnt++;
      for (int i = 1; i < NN; ++i) {
        const double pn = (dd[i] - x) * p - ee2[i - 1] * pm;
        pm = p; p = pn;
        if ((p < 0.0) != (pm < 0.0)) cnt++;
        const double ap = fabs(p);
        if (ap > 1e100)                   { p *= 1e-100; pm *= 1e-100; }
        else if (ap < 1e-100 && ap > 0.0) { p *= 1e100;  pm *= 1e100; }
      }
      bcnt[tid] = cnt;
    }
    __syncthreads();
    if (tid < 17) {
      const double lo = blo[tid], hi = bhi[tid];
      const double w8 = (hi - lo) * 0.125;
      double nlo = lo, nhi = hi;
      for (int jj = 0; jj < 7; ++jj) {
        const double x = lo + w8 * (double)(jj + 1);
        if (bcnt[tid * 7 + jj] <= tid) nlo = x; else { nhi = x; break; }
      }
      blo[tid] = nlo; bhi[tid] = nhi;
    }
    __syncthreads();
  }
  if (tid < 17) lam[tid] = 0.5 * (blo[tid] + bhi[tid]);
  __syncthreads();

  // ---------------- inverse iteration on T (lanes 0..15), compressed LU ----------------
  if (tid < 16) {
    const double lk = lam[tid + 1];
    for (int it = 0; it < 2; ++it) {
      float beta = (float)(dd[0] - lk);
      float gam  = (float)ee[0];
      float rr   = (it == 0) ? startvec(0, tid) : byv[0 * 17 + tid];
      unsigned bw = 0;
      for (int i = 1; i < NN; ++i) {
        const int j = i - 1;
        const float ai = (float)ee[i - 1];
        const float bi = (float)(dd[i] - lk);
        const float ci = (i < NN - 1) ? (float)ee[i] : 0.0f;
        const float ri = (it == 0) ? startvec(i, tid) : byv[i * 17 + tid];
        if (fabsf(beta) >= fabsf(ai)) {
          float piv = (beta == 0.0f) ? 1e-25f : beta;
          const float mm = ai / piv;
          sA [j * 17 + tid] = piv;
          byv[j * 17 + tid] = rr;
          beta = bi - mm * gam;  gam = ci;  rr = ri - mm * rr;
        } else {
          const float mm = beta / ai;
          sA [j * 17 + tid] = mm;
          byv[j * 17 + tid] = ri;
          beta = gam - mm * bi;  gam = -mm * ci;  rr = rr - mm * ri;
          bw |= 1u << (j & 31);
        }
        if ((j & 31) == 31) { swb[tid * 5 + (j >> 5)] = bw; bw = 0; }
      }
      if (beta == 0.0f) beta = 1e-25f;
      sA [127 * 17 + tid] = beta;        // swp[127]=0
      byv[127 * 17 + tid] = rr;
      swb[tid * 5 + 3] = bw;             // bits 96..126 (+127=0)
      float y1 = 0.0f, y2 = 0.0f;
      for (int j = NN - 1; j >= 0; --j) {
        const bool sj = (swb[tid * 5 + (j >> 5)] >> (j & 31)) & 1;
        const bool sjm1 = (j > 0) ? ((swb[tid * 5 + ((j - 1) >> 5)] >> ((j - 1) & 31)) & 1) : false;
        float u0, u1, u2;
        if (sj) {
          u0 = (float)ee[j];
          u1 = (float)(dd[j + 1] - lk);
          u2 = (j < NN - 2) ? (float)ee[j + 1] : 0.0f;
        } else {
          u0 = sA[j * 17 + tid];
          const float ej = (j < NN - 1) ? (float)ee[j] : 0.0f;
          u1 = sjm1 ? (-sA[(j - 1) * 17 + tid] * ej) : ej;
          u2 = 0.0f;
        }
        const float yy = (byv[j * 17 + tid] - u1 * y1 - u2 * y2) / u0;
        byv[j * 17 + tid] = yy;
        y2 = y1; y1 = yy;
      }
      double nrm = 0.0;
      for (int i = 0; i < NN; ++i) { const double v = (double)byv[i * 17 + tid]; nrm += v * v; }
      const double inv = 1.0 / sqrt(nrm);
      for (int i = 0; i < NN; ++i) byv[i * 17 + tid] = (float)((double)byv[i * 17 + tid] * inv);
    }
  }
  __syncthreads();

  // ---------------- MGS ----------------
  for (int kk = 1; kk < 16; ++kk) {
    const int j = tid >> 3, s8 = tid & 7;
    double part = 0.0;
    if (j < kk)
      for (int i = s8 * 16; i < s8 * 16 + 16; ++i)
        part += (double)byv[i * 17 + j] * (double)byv[i * 17 + kk];
    for (int off = 4; off > 0; off >>= 1) part += __shfl_down(part, off, 8);
    __syncthreads();
    if (s8 == 0 && j < kk) dred[j] = part;
    __syncthreads();
    if (tid < NN) {
      double acc = (double)byv[tid * 17 + kk];
      for (int j2 = 0; j2 < kk; ++j2) acc -= dred[j2] * (double)byv[tid * 17 + j2];
      byv[tid * 17 + kk] = (float)acc;
    }
    __syncthreads();
    double p2 = 0.0;
    if (tid < NN) { const double v = (double)byv[tid * 17 + kk]; p2 = v * v; }
    const double n2 = blockReduceSum(p2, red, tid);
    if (tid < NN) byv[tid * 17 + kk] = (float)((double)byv[tid * 17 + kk] / sqrt(n2));
    __syncthreads();
  }

  // ---------------- s_k = t . y_k ; pooled ----------------
  if (tid < NN) {
    const int j = tid >> 3, s8 = tid & 7;
    double part = 0.0;
    for (int i = s8 * 16; i < s8 * 16 + 16; ++i)
      part += (double)tvecf[i] * (double)byv[i * 17 + j];
    for (int off = 4; off > 0; off >>= 1) part += __shfl_down(part, off, 8);
    if (s8 == 0) ssv[j] = part;
  }
  __syncthreads();
  if (tid == 0) {
    float lv[16], ev[16];
    float mx = -1e30f;
    for (int i = 0; i < 16; ++i) { lv[i] = (float)lam[i + 1]; mx = fmaxf(mx, -lv[i]); }
    float se = 0.0f;
    for (int i = 0; i < 16; ++i) { ev[i] = expf(-lv[i] - mx); se += ev[i]; }
    for (int i = 0; i < 16; ++i) pool[i] = (ev[i] / se) * (float)ssv[i];
  }
  __syncthreads();

  // ---------------- MLPs + outputs ----------------
  if (tid < NN) {
    float acc = Bb1[tid];
    for (int i = 0; i < 16; ++i) acc = fmaf(pool[i], W1[i * 128 + tid], acc);
    hbuf[tid] = fmaxf(acc, 0.0f);
  }
  __syncthreads();
  if (tid < 64) {
    float acc = Bb2[tid];
    for (int i = 0; i < 128; ++i) acc = fmaf(hbuf[i], W2[i * 64 + tid], acc);
    comb[tid] = acc;                       // spectral
  } else if (tid < NN) {
    comb[tid] = msv[tid - 64];             // ms
  }
  __syncthreads();
  if (tid < NN) {
    float acc = OB1[tid];
    for (int i = 0; i < 128; ++i) acc = fmaf(comb[i], OW1[i * 128 + tid], acc);
    hbuf[tid] = fmaxf(acc, 0.0f);
  }
  __syncthreads();
  if (tid < 16) {
    float acc = OB2[tid];
    for (int i = 0; i < 128; ++i) acc = fmaf(hbuf[i], OW2[i * 16 + tid], acc);
    zrow[tid] = acc;
  }
  __syncthreads();

  const long zeoff = (long)B * 16;
  const long spoff = (long)B * 32;
  const long svoff = (long)B * 32 + (long)B * 64;
  const long coff  = svoff + (long)B * 16;

  if (tid == 0) {
    const float c = 1.0f / (1.0f + expf(-curv[0]));
    float nrm = 0.0f;
    for (int i = 0; i < 16; ++i) nrm += zrow[i] * zrow[i];
    nrm = sqrtf(nrm);
    const float max_r = 0.95f / sqrtf(c);
    sc[3] = (double)fminf(1.0f, max_r / (nrm + 1e-12f));
    if (b == 0) out[coff] = c;
  }
  __syncthreads();
  if (tid < 16) {
    const float fac = (float)sc[3];
    out[b * 16 + tid]          = zrow[tid] * fac;     // z
    out[zeoff + b * 16 + tid]  = zrow[tid];           // z_euclidean
    out[svoff + b * 16 + tid]  = (float)lam[tid + 1]; // sel_vals
  }
  if (tid < 64) out[spoff + b * 64 + tid] = comb[tid]; // spectral
}

extern "C" void kernel_launch(void* const* d_in, const int* in_sizes, int n_in,
                              void* d_out, int out_size, void* d_ws, size_t ws_size,
                              hipStream_t stream) {
  const float* A    = (const float*)d_in[0];
  const float* F    = (const float*)d_in[1];
  const float* swg  = (const float*)d_in[2];
  const float* curv = (const float*)d_in[3];
  const float* W1   = (const float*)d_in[4];
  const float* Bb1  = (const float*)d_in[5];
  const float* W2   = (const float*)d_in[6];
  const float* Bb2  = (const float*)d_in[7];
  const float* OW1  = (const float*)d_in[8];
  const float* OB1  = (const float*)d_in[9];
  const float* OW2  = (const float*)d_in[10];
  const float* OB2  = (const float*)d_in[11];
  float* out = (float*)d_out;
  const int B = in_sizes[0] / (128 * 128);

  holo_kernel<<<dim3(B), dim3(BLK), 0, stream>>>(
      A, F, swg, curv, W1, Bb1, W2, Bb2, OW1, OB1, OW2, OB2, out, B);
}